// Round 7
// baseline (115.857 us; speedup 1.0000x reference)
//
#include <hip/hip_runtime.h>
#include <hip/hip_bf16.h>
#include <math.h>

// Problem constants
#define BB 64
#define QQ 100
#define NN 16
#define CC 2048            // NUM_CLASSES + 1
#define TIME_WEIGHT 2.0f
#define EOS_COEF 0.1f

__device__ __forceinline__ double readlane_d(double x, int lane) {
    int lo = __builtin_amdgcn_readlane(__double2loint(x), lane);
    int hi = __builtin_amdgcn_readlane(__double2hiint(x), lane);
    return __hiloint2double(hi, lo);
}

// ---------------------------------------------------------------------------
// Kernel 1: per (b,q) row (one wave each):
//   logZ[b,q] = logsumexp(logits[b,q,:])
//   CgT[b][q][n] = -softmax[label_n] + 2*|pt - ts_n|   (row-contiguous in n:
//                  lanes 0..15 write one coalesced 64B burst per row)
//   lsepart[block] = sum over 4 rows of (logZ - logit[class 0])   [EOS nll]
// Block 0 additionally zero-inits the atomic accumulators for kernel 2.
// ---------------------------------------------------------------------------
__global__ __launch_bounds__(256) void lse_cost_kernel(
    const float* __restrict__ logits, const float* __restrict__ ptime,
    const int* __restrict__ labels, const float* __restrict__ tstamp,
    float* __restrict__ logZ, float* __restrict__ CgT,
    float* __restrict__ lsepart, float* __restrict__ sums, int* __restrict__ counter)
{
    if (blockIdx.x == 0 && threadIdx.x == 0) {
        sums[0] = 0.f; sums[1] = 0.f; *counter = 0;
    }
    const int wave = threadIdx.x >> 6;
    const int lane = threadIdx.x & 63;
    const int bq = blockIdx.x * 4 + wave;          // < 6400
    const int b = bq / QQ;
    const float4* row4 = (const float4*)(logits + (size_t)bq * CC);

    float4 v[8];
    #pragma unroll
    for (int c = 0; c < 8; ++c) v[c] = row4[c * 64 + lane];

    // issue the tail gathers early (overlap with reduction latency)
    const float pt = ptime[bq];
    int lab = 0; float ts = 0.f;
    if (lane < NN) {
        lab = labels[b * NN + lane];
        ts  = tstamp[b * NN + lane];
    }

    float m = -INFINITY;
    #pragma unroll
    for (int c = 0; c < 8; ++c)
        m = fmaxf(m, fmaxf(fmaxf(v[c].x, v[c].y), fmaxf(v[c].z, v[c].w)));
    #pragma unroll
    for (int s = 1; s < 64; s <<= 1) m = fmaxf(m, __shfl_xor(m, s, 64));

    float sum = 0.f;
    #pragma unroll
    for (int c = 0; c < 8; ++c)
        sum += expf(v[c].x - m) + expf(v[c].y - m) +
               expf(v[c].z - m) + expf(v[c].w - m);
    #pragma unroll
    for (int s = 1; s < 64; s <<= 1) sum += __shfl_xor(sum, s, 64);

    const float lz = m + logf(sum);
    if (lane == 0) logZ[bq] = lz;

    // cost-matrix entries (lanes 0..15: one target each, coalesced store)
    if (lane < NN) {
        float lg = logits[(size_t)bq * CC + lab];     // L1-hot gather (same row)
        float cc = -expf(lg - lz);
        float ct = fabsf(pt - ts);
        float val = cc + TIME_WEIGHT * ct;
        if (isnan(val)) val = 100.0f;
        else if (isinf(val)) val = (val > 0.f) ? 100.0f : -100.0f;
        CgT[(size_t)bq * NN + lane] = val;
    }

    // EOS nll partial: nll0 = logZ - logit[class 0]
    __shared__ float red[4];
    if (lane == 0) red[wave] = lz - logits[(size_t)bq * CC];
    __syncthreads();
    if (threadIdx.x == 0)
        lsepart[blockIdx.x] = red[0] + red[1] + red[2] + red[3];
}

// ---------------------------------------------------------------------------
// Kernel 2: Jonker-Volgenant assignment, one wave per batch. The cost matrix
// is held in REGISTERS: lane t keeps its two owned columns as 8 float4s
// (loaded with 16B vector loads from the transposed CgT), and the uniform
// row index i0 selects via a nested-ternary cndmask tree (no arrays -> no
// scratch). Selected float converts to double AFTER selection (exact), so
// all double arithmetic stays operation-identical to the numpy reference.
// Min-reduction: 4 xor-shuffle stages within 16-lane rows + 4 readlanes +
// 3 fmin. Winning column via equality ballots, cols 1..64 prioritized over
// 65..100 == np.argmin lowest-index tie-break (fmin returns a bit-exact
// member of the candidate set).
// Fused tail: CE correction + L1 time partials -> device atomics; last of
// the 64 blocks folds lsepart and writes the final scalar loss.
// ---------------------------------------------------------------------------
__global__ __launch_bounds__(64) void hungarian_kernel(
    const float* __restrict__ CgT, const float* __restrict__ logits,
    const float* __restrict__ ptime, const int* __restrict__ labels,
    const float* __restrict__ tstamp, const float* __restrict__ logZ,
    const float* __restrict__ lsepart, float* __restrict__ sums,
    int* __restrict__ counter, float* __restrict__ out)
{
    const int b = blockIdx.x;
    const int t = threadIdx.x;

    __shared__ int qsl[NN];

    // Lane t owns columns jc0 = t+1 and (if <=100) jc1 = t+65 (1-based).
    const int jc0 = t + 1;
    const int jc1 = t + 65;
    const bool has2 = (jc1 <= QQ);
    const int t2 = has2 ? (t + 64) : t;            // clamp keeps loads in-bounds

    // owned cost columns in registers (16 floats each, as 4 float4s)
    const float* colbase = CgT + (size_t)b * QQ * NN;
    const float4* cp0 = (const float4*)(colbase + t * NN);
    const float4* cp1 = (const float4*)(colbase + t2 * NN);
    const float4 a0 = cp0[0], a1 = cp0[1], a2 = cp0[2], a3 = cp0[3];
    const float4 b0 = cp1[0], b1 = cp1[1], b2 = cp1[2], b3 = cp1[3];

    double v0 = 0.0, v1 = 0.0;          // column potentials (owned)
    double ureg = 0.0;                  // lane r holds u[r+1] (lanes 0..15)
    int preg0 = 0, preg1 = 0;           // p[jc0], p[jc1] (0 = free)
    const double INF = __builtin_inf();

    for (int i = 1; i <= NN; ++i) {
        double minv0 = INF, minv1 = INF;
        bool used0 = false, used1 = false;
        int way0 = 0, way1 = 0;
        bool inTree = (t == i - 1);     // p[0] = i enters the tree at start
        int j0 = 0;
        int i0 = i;                      // p[0]

        while (true) {
            used0 |= (j0 == jc0);
            used1 |= (j0 == jc1);
            inTree = inTree || (t == i0 - 1);
            const double u_i0 = readlane_d(ureg, i0 - 1);

            // register select of row (i0-1)'s two cost entries: cndmask tree
            const int mrow = i0 - 1;     // wave-uniform, 0..15
            float4 ha = (mrow & 8) ? ((mrow & 4) ? a3 : a2)
                                   : ((mrow & 4) ? a1 : a0);
            float4 hb = (mrow & 8) ? ((mrow & 4) ? b3 : b2)
                                   : ((mrow & 4) ? b1 : b0);
            float ca = (mrow & 2) ? ((mrow & 1) ? ha.w : ha.z)
                                  : ((mrow & 1) ? ha.y : ha.x);
            float cb = (mrow & 2) ? ((mrow & 1) ? hb.w : hb.z)
                                  : ((mrow & 1) ? hb.y : hb.x);

            if (!used0) {
                double cur = (double)ca - u_i0 - v0;
                if (cur < minv0) { minv0 = cur; way0 = j0; }
            }
            if (has2 && !used1) {
                double cur = (double)cb - u_i0 - v1;
                if (cur < minv1) { minv1 = cur; way1 = j0; }
            }

            // value-only min reduction: 4 xor stages within 16-lane rows,
            // then 4 readlanes + 3 fmin across rows.
            double m0 = used0 ? INF : minv0;
            double m1 = (has2 && !used1) ? minv1 : INF;
            double gmin = fmin(m0, m1);
            #pragma unroll
            for (int s = 1; s < 16; s <<= 1)
                gmin = fmin(gmin, __shfl_xor(gmin, s, 64));
            {
                double h0 = readlane_d(gmin, 0);
                double h1 = readlane_d(gmin, 16);
                double h2 = readlane_d(gmin, 32);
                double h3 = readlane_d(gmin, 48);
                gmin = fmin(fmin(h0, h1), fmin(h2, h3));
            }
            // winning column: ballot A (cols 1..64) has priority, then B
            unsigned long long A  = __ballot(!used0 && (minv0 == gmin));
            unsigned long long Bm = __ballot(has2 && !used1 && (minv1 == gmin));
            int j1 = (A != 0ull) ? ((int)__builtin_ctzll(A) + 1)
                                 : ((int)__builtin_ctzll(Bm) + 65);
            const double delta = gmin;

            if (inTree) ureg += delta;                   // u[p[used]] += delta
            if (used0) v0 -= delta; else minv0 -= delta;
            if (has2) { if (used1) v1 -= delta; else minv1 -= delta; }

            j0 = j1;
            int pj = (j0 <= 64) ? __builtin_amdgcn_readlane(preg0, j0 - 1)
                                : __builtin_amdgcn_readlane(preg1, j0 - 65);
            if (pj == 0) break;
            i0 = pj;
        }

        // augment along the alternating path (uniform walk)
        while (j0 != 0) {
            int jn = (j0 <= 64) ? __builtin_amdgcn_readlane(way0, j0 - 1)
                                : __builtin_amdgcn_readlane(way1, j0 - 65);
            int pv;
            if (jn == 0) pv = i;
            else pv = (jn <= 64) ? __builtin_amdgcn_readlane(preg0, jn - 1)
                                 : __builtin_amdgcn_readlane(preg1, jn - 65);
            if (j0 == jc0) preg0 = pv;
            if (has2 && j0 == jc1) preg1 = pv;
            j0 = jn;
        }
    }

    // extract matches: qsl[target row] = column
    if (preg0 > 0) qsl[preg0 - 1] = jc0 - 1;
    if (has2 && preg1 > 0) qsl[preg1 - 1] = jc1 - 1;
    __syncthreads();

    // fused tail: CE correction + time-loss partials for this batch
    float corr = 0.f, tl = 0.f;
    if (t < NN) {
        int qcol = qsl[t];
        int lab = labels[b * NN + t];
        int bq = b * QQ + qcol;
        float lz = logZ[bq];
        float lgm = logits[(size_t)bq * CC + lab];
        float lg0 = logits[(size_t)bq * CC];
        corr = (lz - lgm) - EOS_COEF * (lz - lg0);
        tl = fabsf(ptime[bq] - tstamp[b * NN + t]);
    }
    #pragma unroll
    for (int s = 1; s < 64; s <<= 1) {
        corr += __shfl_xor(corr, s, 64);
        tl   += __shfl_xor(tl, s, 64);
    }

    int old = 0;
    if (t == 0) {
        atomicAdd(&sums[0], corr);
        atomicAdd(&sums[1], tl);
        __threadfence();                 // release partials before counter bump
        old = atomicAdd(counter, 1);
    }
    old = __shfl(old, 0, 64);
    if (old == BB - 1) {                 // last block finalizes
        __threadfence();                 // acquire others' partials
        float r0 = 0.f;
        #pragma unroll
        for (int k = 0; k < 25; ++k) r0 += lsepart[t + 64 * k];   // 1600 = 64*25
        #pragma unroll
        for (int s = 1; s < 64; s <<= 1) r0 += __shfl_xor(r0, s, 64);
        if (t == 0) {
            float s0 = atomicAdd(&sums[0], 0.0f);
            float s1 = atomicAdd(&sums[1], 0.0f);
            const float sum_w = (float)(BB * NN) * 1.0f
                              + (float)(BB * (QQ - NN)) * EOS_COEF;   // 1561.6
            float loss_ce = (EOS_COEF * r0 + s0) / sum_w;
            float loss_t  = s1 / (float)(BB * NN);
            out[0] = loss_ce + TIME_WEIGHT * loss_t;
        }
    }
}

// ---------------------------------------------------------------------------
// Workspace layout (bytes):
//   [0,      25600)  : float logZ[6400]
//   [25600, 435200)  : float CgT[64*100*16]   (transposed cost matrix)
//   [435200, 441600) : float lsepart[1600]
//   [441600, 441608) : float sums[2]   {ce_corr, time}   (zeroed by kernel 1)
//   [441608, 441612) : int   counter                     (zeroed by kernel 1)
// ---------------------------------------------------------------------------
extern "C" void kernel_launch(void* const* d_in, const int* in_sizes, int n_in,
                              void* d_out, int out_size, void* d_ws, size_t ws_size,
                              hipStream_t stream) {
    const float* logits = (const float*)d_in[0];   // [B,Q,2048]
    const float* ptime  = (const float*)d_in[1];   // [B,Q,1]
    const int*   labels = (const int*)d_in[2];     // [B,N]
    const float* tstamp = (const float*)d_in[3];   // [B,N,1]
    float* out = (float*)d_out;

    char* ws = (char*)d_ws;
    float* logZ    = (float*)ws;
    float* CgT     = (float*)(ws + 25600);
    float* lsepart = (float*)(ws + 435200);
    float* sums    = (float*)(ws + 441600);
    int*   counter = (int*)(ws + 441608);

    lse_cost_kernel<<<1600, 256, 0, stream>>>(logits, ptime, labels, tstamp,
                                              logZ, CgT, lsepart, sums, counter);
    hungarian_kernel<<<BB, 64, 0, stream>>>(CgT, logits, ptime, labels, tstamp,
                                            logZ, lsepart, sums, counter, out);
}

// Round 8
// 110.309 us; speedup vs baseline: 1.0503x; 1.0503x over previous
//
#include <hip/hip_runtime.h>
#include <hip/hip_bf16.h>
#include <math.h>

// Problem constants
#define BB 64
#define QQ 100
#define NN 16
#define CC 2048            // NUM_CLASSES + 1
#define TIME_WEIGHT 2.0f
#define EOS_COEF 0.1f

__device__ __forceinline__ double readlane_d(double x, int lane) {
    int lo = __builtin_amdgcn_readlane(__double2loint(x), lane);
    int hi = __builtin_amdgcn_readlane(__double2hiint(x), lane);
    return __hiloint2double(hi, lo);
}

// ---------------------------------------------------------------------------
// Kernel 1: per (b,q) row (one wave each):
//   logZ[b,q] = logsumexp(logits[b,q,:])
//   CgT[b][q][n] = -softmax[label_n] + 2*|pt - ts_n|   (row-contiguous in n:
//                  lanes 0..15 write one coalesced 64B burst per row)
//   lsepart[block] = sum over 4 rows of (logZ - logit[class 0])   [EOS nll]
// Block 0 additionally zero-inits the atomic accumulators for kernel 2.
// ---------------------------------------------------------------------------
__global__ __launch_bounds__(256) void lse_cost_kernel(
    const float* __restrict__ logits, const float* __restrict__ ptime,
    const int* __restrict__ labels, const float* __restrict__ tstamp,
    float* __restrict__ logZ, float* __restrict__ CgT,
    float* __restrict__ lsepart, float* __restrict__ sums, int* __restrict__ counter)
{
    if (blockIdx.x == 0 && threadIdx.x == 0) {
        sums[0] = 0.f; sums[1] = 0.f; *counter = 0;
    }
    const int wave = threadIdx.x >> 6;
    const int lane = threadIdx.x & 63;
    const int bq = blockIdx.x * 4 + wave;          // < 6400
    const int b = bq / QQ;
    const float4* row4 = (const float4*)(logits + (size_t)bq * CC);

    float4 v[8];
    #pragma unroll
    for (int c = 0; c < 8; ++c) v[c] = row4[c * 64 + lane];

    float m = -INFINITY;
    #pragma unroll
    for (int c = 0; c < 8; ++c)
        m = fmaxf(m, fmaxf(fmaxf(v[c].x, v[c].y), fmaxf(v[c].z, v[c].w)));
    #pragma unroll
    for (int s = 1; s < 64; s <<= 1) m = fmaxf(m, __shfl_xor(m, s, 64));

    float sum = 0.f;
    #pragma unroll
    for (int c = 0; c < 8; ++c)
        sum += expf(v[c].x - m) + expf(v[c].y - m) +
               expf(v[c].z - m) + expf(v[c].w - m);
    #pragma unroll
    for (int s = 1; s < 64; s <<= 1) sum += __shfl_xor(sum, s, 64);

    const float lz = m + logf(sum);
    if (lane == 0) logZ[bq] = lz;

    // cost-matrix entries (lanes 0..15: one target each, coalesced store)
    const float pt = ptime[bq];
    if (lane < NN) {
        int lab = labels[b * NN + lane];
        float lg = logits[(size_t)bq * CC + lab];     // L1-hot gather (same row)
        float cc = -expf(lg - lz);
        float ct = fabsf(pt - tstamp[b * NN + lane]);
        float val = cc + TIME_WEIGHT * ct;
        if (isnan(val)) val = 100.0f;
        else if (isinf(val)) val = (val > 0.f) ? 100.0f : -100.0f;
        CgT[(size_t)bq * NN + lane] = val;
    }

    // EOS nll partial: nll0 = logZ - logit[class 0]
    __shared__ float red[4];
    if (lane == 0) red[wave] = lz - logits[(size_t)bq * CC];
    __syncthreads();
    if (threadIdx.x == 0)
        lsepart[blockIdx.x] = red[0] + red[1] + red[2] + red[3];
}

// ---------------------------------------------------------------------------
// Kernel 2: Jonker-Volgenant assignment, one wave per batch. The cost matrix
// is register-resident: lane t keeps its two owned columns as 8 float4s
// (16B vector loads from the transposed CgT); the uniform row index selects
// via a nested-ternary cndmask tree (no arrays -> no scratch). Selected
// float converts to double AFTER selection (exact), so all double
// arithmetic stays operation-identical to the numpy reference.
// Min-reduction (f64, 64 lanes): two-phase 8-way gather --
//   phase 1: 8 __shfl gathers (16 pipelined ds_bpermutes, ONE drain) give
//            lane t all 8 values of chunk (t&7); depth-3 fmin tree.
//   phase 2: chunk-mins now at uniform lanes 0..7 -> 8 v_readlane pairs +
//            depth-3 fmin tree. All lanes end with gmin.
// fmin is associative for non-NaN and +-0 compares equal, so gmin and the
// equality-ballot winner (cols 1..64 prioritized over 65..100) reproduce
// np.argmin's lowest-index tie-break bit-exactly.
// Fused tail: CE correction + L1 time partials -> device atomics; last of
// the 64 blocks folds lsepart and writes the final scalar loss.
// ---------------------------------------------------------------------------
__global__ __launch_bounds__(64) void hungarian_kernel(
    const float* __restrict__ CgT, const float* __restrict__ logits,
    const float* __restrict__ ptime, const int* __restrict__ labels,
    const float* __restrict__ tstamp, const float* __restrict__ logZ,
    const float* __restrict__ lsepart, float* __restrict__ sums,
    int* __restrict__ counter, float* __restrict__ out)
{
    const int b = blockIdx.x;
    const int t = threadIdx.x;

    __shared__ int qsl[NN];

    // Lane t owns columns jc0 = t+1 and (if <=100) jc1 = t+65 (1-based).
    const int jc0 = t + 1;
    const int jc1 = t + 65;
    const bool has2 = (jc1 <= QQ);
    const int t2 = has2 ? (t + 64) : t;            // clamp keeps loads in-bounds

    // owned cost columns in registers (16 floats each, as 4 float4s)
    const float* colbase = CgT + (size_t)b * QQ * NN;
    const float4* cp0 = (const float4*)(colbase + t * NN);
    const float4* cp1 = (const float4*)(colbase + t2 * NN);
    const float4 a0 = cp0[0], a1 = cp0[1], a2 = cp0[2], a3 = cp0[3];
    const float4 b0 = cp1[0], b1 = cp1[1], b2 = cp1[2], b3 = cp1[3];

    double v0 = 0.0, v1 = 0.0;          // column potentials (owned)
    double ureg = 0.0;                  // lane r holds u[r+1] (lanes 0..15)
    int preg0 = 0, preg1 = 0;           // p[jc0], p[jc1] (0 = free)
    const double INF = __builtin_inf();
    const int gbase = (t & 7) << 3;     // base lane of my gather chunk

    for (int i = 1; i <= NN; ++i) {
        double minv0 = INF, minv1 = INF;
        bool used0 = false, used1 = false;
        int way0 = 0, way1 = 0;
        bool inTree = (t == i - 1);     // p[0] = i enters the tree at start
        int j0 = 0;
        int i0 = i;                      // p[0]

        while (true) {
            used0 |= (j0 == jc0);
            used1 |= (j0 == jc1);
            inTree = inTree || (t == i0 - 1);
            const double u_i0 = readlane_d(ureg, i0 - 1);

            // register select of row (i0-1)'s two cost entries: cndmask tree
            const int mrow = i0 - 1;     // wave-uniform, 0..15
            float4 ha = (mrow & 8) ? ((mrow & 4) ? a3 : a2)
                                   : ((mrow & 4) ? a1 : a0);
            float4 hb = (mrow & 8) ? ((mrow & 4) ? b3 : b2)
                                   : ((mrow & 4) ? b1 : b0);
            float ca = (mrow & 2) ? ((mrow & 1) ? ha.w : ha.z)
                                  : ((mrow & 1) ? ha.y : ha.x);
            float cb = (mrow & 2) ? ((mrow & 1) ? hb.w : hb.z)
                                  : ((mrow & 1) ? hb.y : hb.x);

            if (!used0) {
                double cur = (double)ca - u_i0 - v0;
                if (cur < minv0) { minv0 = cur; way0 = j0; }
            }
            if (has2 && !used1) {
                double cur = (double)cb - u_i0 - v1;
                if (cur < minv1) { minv1 = cur; way1 = j0; }
            }

            // ---- two-phase 8-way-gather min reduction ----
            double m0 = used0 ? INF : minv0;
            double m1 = (has2 && !used1) ? minv1 : INF;
            double mm = fmin(m0, m1);

            double g0 = __shfl(mm, gbase + 0, 64);
            double g1 = __shfl(mm, gbase + 1, 64);
            double g2 = __shfl(mm, gbase + 2, 64);
            double g3 = __shfl(mm, gbase + 3, 64);
            double g4 = __shfl(mm, gbase + 4, 64);
            double g5 = __shfl(mm, gbase + 5, 64);
            double g6 = __shfl(mm, gbase + 6, 64);
            double g7 = __shfl(mm, gbase + 7, 64);
            double cmin = fmin(fmin(fmin(g0, g1), fmin(g2, g3)),
                               fmin(fmin(g4, g5), fmin(g6, g7)));
            // chunk-min of chunk c now lives in lanes {c, c+8, ...}
            double h0 = readlane_d(cmin, 0);
            double h1 = readlane_d(cmin, 1);
            double h2 = readlane_d(cmin, 2);
            double h3 = readlane_d(cmin, 3);
            double h4 = readlane_d(cmin, 4);
            double h5 = readlane_d(cmin, 5);
            double h6 = readlane_d(cmin, 6);
            double h7 = readlane_d(cmin, 7);
            double gmin = fmin(fmin(fmin(h0, h1), fmin(h2, h3)),
                               fmin(fmin(h4, h5), fmin(h6, h7)));

            // winning column: ballot A (cols 1..64) has priority, then B
            unsigned long long A  = __ballot(!used0 && (minv0 == gmin));
            unsigned long long Bm = __ballot(has2 && !used1 && (minv1 == gmin));
            int j1 = (A != 0ull) ? ((int)__builtin_ctzll(A) + 1)
                                 : ((int)__builtin_ctzll(Bm) + 65);
            const double delta = gmin;

            if (inTree) ureg += delta;                   // u[p[used]] += delta
            if (used0) v0 -= delta; else minv0 -= delta;
            if (has2) { if (used1) v1 -= delta; else minv1 -= delta; }

            j0 = j1;
            int pj = (j0 <= 64) ? __builtin_amdgcn_readlane(preg0, j0 - 1)
                                : __builtin_amdgcn_readlane(preg1, j0 - 65);
            if (pj == 0) break;
            i0 = pj;
        }

        // augment along the alternating path (uniform walk)
        while (j0 != 0) {
            int jn = (j0 <= 64) ? __builtin_amdgcn_readlane(way0, j0 - 1)
                                : __builtin_amdgcn_readlane(way1, j0 - 65);
            int pv;
            if (jn == 0) pv = i;
            else pv = (jn <= 64) ? __builtin_amdgcn_readlane(preg0, jn - 1)
                                 : __builtin_amdgcn_readlane(preg1, jn - 65);
            if (j0 == jc0) preg0 = pv;
            if (has2 && j0 == jc1) preg1 = pv;
            j0 = jn;
        }
    }

    // extract matches: qsl[target row] = column
    if (preg0 > 0) qsl[preg0 - 1] = jc0 - 1;
    if (has2 && preg1 > 0) qsl[preg1 - 1] = jc1 - 1;
    __syncthreads();

    // fused tail: CE correction + time-loss partials for this batch
    float corr = 0.f, tl = 0.f;
    if (t < NN) {
        int qcol = qsl[t];
        int lab = labels[b * NN + t];
        int bq = b * QQ + qcol;
        float lz = logZ[bq];
        float lgm = logits[(size_t)bq * CC + lab];
        float lg0 = logits[(size_t)bq * CC];
        corr = (lz - lgm) - EOS_COEF * (lz - lg0);
        tl = fabsf(ptime[bq] - tstamp[b * NN + t]);
    }
    #pragma unroll
    for (int s = 1; s < 64; s <<= 1) {
        corr += __shfl_xor(corr, s, 64);
        tl   += __shfl_xor(tl, s, 64);
    }

    int old = 0;
    if (t == 0) {
        atomicAdd(&sums[0], corr);
        atomicAdd(&sums[1], tl);
        __threadfence();                 // release partials before counter bump
        old = atomicAdd(counter, 1);
    }
    old = __shfl(old, 0, 64);
    if (old == BB - 1) {                 // last block finalizes
        __threadfence();                 // acquire others' partials
        float r0 = 0.f;
        #pragma unroll
        for (int k = 0; k < 25; ++k) r0 += lsepart[t + 64 * k];   // 1600 = 64*25
        #pragma unroll
        for (int s = 1; s < 64; s <<= 1) r0 += __shfl_xor(r0, s, 64);
        if (t == 0) {
            float s0 = atomicAdd(&sums[0], 0.0f);
            float s1 = atomicAdd(&sums[1], 0.0f);
            const float sum_w = (float)(BB * NN) * 1.0f
                              + (float)(BB * (QQ - NN)) * EOS_COEF;   // 1561.6
            float loss_ce = (EOS_COEF * r0 + s0) / sum_w;
            float loss_t  = s1 / (float)(BB * NN);
            out[0] = loss_ce + TIME_WEIGHT * loss_t;
        }
    }
}

// ---------------------------------------------------------------------------
// Workspace layout (bytes):
//   [0,      25600)  : float logZ[6400]
//   [25600, 435200)  : float CgT[64*100*16]   (transposed cost matrix)
//   [435200, 441600) : float lsepart[1600]
//   [441600, 441608) : float sums[2]   {ce_corr, time}   (zeroed by kernel 1)
//   [441608, 441612) : int   counter                     (zeroed by kernel 1)
// ---------------------------------------------------------------------------
extern "C" void kernel_launch(void* const* d_in, const int* in_sizes, int n_in,
                              void* d_out, int out_size, void* d_ws, size_t ws_size,
                              hipStream_t stream) {
    const float* logits = (const float*)d_in[0];   // [B,Q,2048]
    const float* ptime  = (const float*)d_in[1];   // [B,Q,1]
    const int*   labels = (const int*)d_in[2];     // [B,N]
    const float* tstamp = (const float*)d_in[3];   // [B,N,1]
    float* out = (float*)d_out;

    char* ws = (char*)d_ws;
    float* logZ    = (float*)ws;
    float* CgT     = (float*)(ws + 25600);
    float* lsepart = (float*)(ws + 435200);
    float* sums    = (float*)(ws + 441600);
    int*   counter = (int*)(ws + 441608);

    lse_cost_kernel<<<1600, 256, 0, stream>>>(logits, ptime, labels, tstamp,
                                              logZ, CgT, lsepart, sums, counter);
    hungarian_kernel<<<BB, 64, 0, stream>>>(CgT, logits, ptime, labels, tstamp,
                                            logZ, lsepart, sums, counter, out);
}